// Round 2
// baseline (553.300 us; speedup 1.0000x reference)
//
#include <hip/hip_runtime.h>
#include <math.h>

#define D 64
#define NUM_USERS 100000
#define NUM_ITEMS 50000
#define N_NODES 150000   // NUM_USERS + NUM_ITEMS
#define NNZ 2400000
#define BATCH 8192
#define NEG_SLOPE 0.1f
#define EPS_NRM 1e-12f

#define NH      150016              // N_NODES padded to 256 multiple
#define NBH     (NH / 256)          // 586 scan blocks
#define VSCALE  16383.f             // 14-bit val quantization

typedef unsigned short ushort_t;

__device__ __forceinline__ float wave_sum64(float v) {
    #pragma unroll
    for (int off = 32; off > 0; off >>= 1)
        v += __shfl_xor(v, off, 64);
    return v;
}

__device__ __forceinline__ int wave_sum64_i(int v) {
    #pragma unroll
    for (int off = 32; off > 0; off >>= 1)
        v += __shfl_xor(v, off, 64);
    return v;
}

__device__ __forceinline__ float bf2f(ushort_t u) {
    return __uint_as_float(((unsigned)u) << 16);
}
__device__ __forceinline__ ushort_t f2bf(float f) {
    unsigned x = __float_as_uint(f);
    unsigned r = (x + 0x7FFFu + ((x >> 16) & 1u)) >> 16;   // RNE
    return (ushort_t)r;
}

// ---------- CSR build: 3-pass counting sort, global atomics ----------
// rows are uniform-random over 150K -> avg 16 hits/counter, low contention.

__global__ void row_hist(const int* __restrict__ rows, int* __restrict__ hist) {
    int i = blockIdx.x * 256 + threadIdx.x;
    int stride = gridDim.x * 256;
    const int4* r4 = (const int4*)rows;
    for (; i < NNZ / 4; i += stride) {
        int4 r = r4[i];
        atomicAdd(&hist[r.x], 1);
        atomicAdd(&hist[r.y], 1);
        atomicAdd(&hist[r.z], 1);
        atomicAdd(&hist[r.w], 1);
    }
}

__global__ void scan1_kernel(const int* __restrict__ in, int* __restrict__ out,
                             int* __restrict__ bsums, int n) {
    int tid = threadIdx.x, gid = blockIdx.x * 256 + tid;
    int v = (gid < n) ? in[gid] : 0;
    int lane = tid & 63, w = tid >> 6;
    int s = v;
    #pragma unroll
    for (int off = 1; off < 64; off <<= 1) {
        int t = __shfl_up(s, off, 64);
        if (lane >= off) s += t;
    }
    __shared__ int wsum[4];
    if (lane == 63) wsum[w] = s;
    __syncthreads();
    if (tid == 0) {
        int a = 0;
        #pragma unroll
        for (int i = 0; i < 4; i++) { int t = wsum[i]; wsum[i] = a; a += t; }
    }
    __syncthreads();
    int incl = s + wsum[w];
    if (gid < n) out[gid] = incl - v;           // exclusive
    if (tid == 255) bsums[blockIdx.x] = incl;   // block total (unscanned)
}

// fused: each block reduces bsums[0..b) itself, then adds to its 256 elems.
// also emits a second copy (cursor) for the scatter pass.
__global__ void scan3_kernel(int* __restrict__ out, int* __restrict__ cursor,
                             const int* __restrict__ bsums, int n) {
    __shared__ int wtot[4];
    __shared__ int total;
    int b = blockIdx.x, tid = threadIdx.x;
    int lane = tid & 63, w = tid >> 6;
    int partial = 0;
    for (int i = tid; i < b; i += 256) partial += bsums[i];
    partial = wave_sum64_i(partial);
    if (lane == 0) wtot[w] = partial;
    __syncthreads();
    if (tid == 0) total = wtot[0] + wtot[1] + wtot[2] + wtot[3];
    __syncthreads();
    int gid = b * 256 + tid;
    if (gid < n) {
        int v = out[gid] + total;
        out[gid] = v;
        cursor[gid] = v;
    }
}

// one pass: read (row,col,val), bump per-row cursor, write final 4B packed entry.
// row-internal edge order is arbitrary (summation order only).
__global__ void csr_scatter(const int* __restrict__ rows, const int* __restrict__ cols,
                            const float* __restrict__ vals, int* __restrict__ cursor,
                            unsigned* __restrict__ es) {
    int i = blockIdx.x * 256 + threadIdx.x;
    int stride = gridDim.x * 256;
    const int4*   r4 = (const int4*)rows;
    const int4*   c4 = (const int4*)cols;
    const float4* v4 = (const float4*)vals;
    for (; i < NNZ / 4; i += stride) {
        int4 r = r4[i];
        int4 c = c4[i];
        float4 v = v4[i];
        int p0 = atomicAdd(&cursor[r.x], 1);
        es[p0] = (unsigned)c.x | ((unsigned)(v.x * VSCALE + 0.5f) << 18);
        int p1 = atomicAdd(&cursor[r.y], 1);
        es[p1] = (unsigned)c.y | ((unsigned)(v.y * VSCALE + 0.5f) << 18);
        int p2 = atomicAdd(&cursor[r.z], 1);
        es[p2] = (unsigned)c.z | ((unsigned)(v.z * VSCALE + 0.5f) << 18);
        int p3 = atomicAdd(&cursor[r.w], 1);
        es[p3] = (unsigned)c.w | ((unsigned)(v.w * VSCALE + 0.5f) << 18);
    }
}

// ---------- GCN ----------
__global__ void init_kernel(const float* __restrict__ upref,
                            const float* __restrict__ ipref,
                            ushort_t* __restrict__ p0) {
    int row  = blockIdx.x * 4 + (threadIdx.x >> 6);
    int lane = threadIdx.x & 63;
    if (row >= N_NODES) return;
    float x = (row < NUM_USERS) ? upref[(size_t)row * D + lane]
                                : ipref[(size_t)(row - NUM_USERS) * D + lane];
    x = (x >= 0.f) ? x : NEG_SLOPE * x;
    float norm = sqrtf(wave_sum64(x * x));
    float y = x / fmaxf(norm, EPS_NRM);
    p0[(size_t)row * D + lane] = f2bf(y);
}

// one wave per row; 8 edge-slots (sub = lane>>3), 8 features/lane (fl = lane&7);
// 2x unrolled; es entries are 4B packed col(18)|valq(14).
// Epilogue: transpose-butterfly over sub bits so lane (sub,fl) ends holding the
// full sum for feature fl*8+sub -> one lrelu/f2bf/2B-store per lane, no divergence.
__global__ void gather_kernel(const int* __restrict__ rowptr,
                              const unsigned* __restrict__ es,
                              const ushort_t* __restrict__ p,
                              ushort_t* __restrict__ pn) {
    int row  = blockIdx.x * 4 + (threadIdx.x >> 6);
    int lane = threadIdx.x & 63;
    if (row >= N_NODES) return;
    int sub = lane >> 3;
    int fl  = lane & 7;
    int beg = rowptr[row], end = rowptr[row + 1];

    float a[8];
    #pragma unroll
    for (int k = 0; k < 8; k++) a[k] = 0.f;

    const float vs = 1.f / VSCALE;
    int e = beg + sub;
    while (e + 8 < end) {
        unsigned ev0 = es[e];
        unsigned ev1 = es[e + 8];
        const uint4 q0 = *(const uint4*)(p + (((ev0 & 0x3FFFFu) << 6) | (fl << 3)));
        const uint4 q1 = *(const uint4*)(p + (((ev1 & 0x3FFFFu) << 6) | (fl << 3)));
        float v0 = (float)(ev0 >> 18) * vs;
        float v1 = (float)(ev1 >> 18) * vs;
        a[0] = fmaf(v0, __uint_as_float(q0.x << 16),         a[0]);
        a[1] = fmaf(v0, __uint_as_float(q0.x & 0xFFFF0000u), a[1]);
        a[2] = fmaf(v0, __uint_as_float(q0.y << 16),         a[2]);
        a[3] = fmaf(v0, __uint_as_float(q0.y & 0xFFFF0000u), a[3]);
        a[4] = fmaf(v0, __uint_as_float(q0.z << 16),         a[4]);
        a[5] = fmaf(v0, __uint_as_float(q0.z & 0xFFFF0000u), a[5]);
        a[6] = fmaf(v0, __uint_as_float(q0.w << 16),         a[6]);
        a[7] = fmaf(v0, __uint_as_float(q0.w & 0xFFFF0000u), a[7]);
        a[0] = fmaf(v1, __uint_as_float(q1.x << 16),         a[0]);
        a[1] = fmaf(v1, __uint_as_float(q1.x & 0xFFFF0000u), a[1]);
        a[2] = fmaf(v1, __uint_as_float(q1.y << 16),         a[2]);
        a[3] = fmaf(v1, __uint_as_float(q1.y & 0xFFFF0000u), a[3]);
        a[4] = fmaf(v1, __uint_as_float(q1.z << 16),         a[4]);
        a[5] = fmaf(v1, __uint_as_float(q1.z & 0xFFFF0000u), a[5]);
        a[6] = fmaf(v1, __uint_as_float(q1.w << 16),         a[6]);
        a[7] = fmaf(v1, __uint_as_float(q1.w & 0xFFFF0000u), a[7]);
        e += 16;
    }
    if (e < end) {
        unsigned ev = es[e];
        const uint4 q = *(const uint4*)(p + (((ev & 0x3FFFFu) << 6) | (fl << 3)));
        float v = (float)(ev >> 18) * vs;
        a[0] = fmaf(v, __uint_as_float(q.x << 16),         a[0]);
        a[1] = fmaf(v, __uint_as_float(q.x & 0xFFFF0000u), a[1]);
        a[2] = fmaf(v, __uint_as_float(q.y << 16),         a[2]);
        a[3] = fmaf(v, __uint_as_float(q.y & 0xFFFF0000u), a[3]);
        a[4] = fmaf(v, __uint_as_float(q.z << 16),         a[4]);
        a[5] = fmaf(v, __uint_as_float(q.z & 0xFFFF0000u), a[5]);
        a[6] = fmaf(v, __uint_as_float(q.w << 16),         a[6]);
        a[7] = fmaf(v, __uint_as_float(q.w & 0xFFFF0000u), a[7]);
    }

    // --- transpose-butterfly reduce over the 8 sub-groups ---
    bool s0 = (sub & 1) != 0, s1 = (sub & 2) != 0, s2 = (sub & 4) != 0;
    float b[4];
    #pragma unroll
    for (int j = 0; j < 4; j++) {
        float send = s0 ? a[2 * j]     : a[2 * j + 1];
        float keep = s0 ? a[2 * j + 1] : a[2 * j];
        b[j] = keep + __shfl_xor(send, 8, 64);
    }
    float c[2];
    #pragma unroll
    for (int i = 0; i < 2; i++) {
        float send = s1 ? b[2 * i]     : b[2 * i + 1];
        float keep = s1 ? b[2 * i + 1] : b[2 * i];
        c[i] = keep + __shfl_xor(send, 16, 64);
    }
    float y;
    {
        float send = s2 ? c[0] : c[1];
        float keep = s2 ? c[1] : c[0];
        y = keep + __shfl_xor(send, 32, 64);
    }

    // lane now owns feature fl*8+sub of this row
    y = (y >= 0.f) ? y : NEG_SLOPE * y;
    float ss = wave_sum64(y * y);
    float inv = 1.f / fmaxf(sqrtf(ss), EPS_NRM);
    pn[(size_t)row * D + fl * 8 + sub] = f2bf(y * inv);
}

// one wave per batch element: sum 4 layer rows for the user once, then 3 item dots.
__global__ void score_kernel(const int* __restrict__ users,
                             const int* __restrict__ it0,
                             const int* __restrict__ it1,
                             const int* __restrict__ it2,
                             const ushort_t* __restrict__ p0,
                             const ushort_t* __restrict__ p1,
                             const ushort_t* __restrict__ p2,
                             const ushort_t* __restrict__ p3,
                             float* __restrict__ out) {
    int b    = blockIdx.x * 4 + (threadIdx.x >> 6);
    int lane = threadIdx.x & 63;
    if (b >= BATCH) return;
    int u = users[b];
    size_t uo = (size_t)u * D + lane;
    float uf = bf2f(p0[uo]) + bf2f(p1[uo]) + bf2f(p2[uo]) + bf2f(p3[uo]);

    int its[3];
    its[0] = it0[b]; its[1] = it1[b]; its[2] = it2[b];
    #pragma unroll
    for (int k = 0; k < 3; k++) {
        size_t io = (size_t)(NUM_USERS + its[k]) * D + lane;
        float itf = bf2f(p0[io]) + bf2f(p1[io]) + bf2f(p2[io]) + bf2f(p3[io]);
        float s = wave_sum64(uf * itf) * 0.0625f;
        if (lane == 0)
            out[k * BATCH + b] = 1.f / (1.f + expf(-s));
    }
}

extern "C" void kernel_launch(void* const* d_in, const int* in_sizes, int n_in,
                              void* d_out, int out_size, void* d_ws, size_t ws_size,
                              hipStream_t stream) {
    const int*   users  = (const int*)  d_in[0];
    const int*   adj    = (const int*)  d_in[1];
    const int*   weak   = (const int*)  d_in[2];
    const int*   strong = (const int*)  d_in[3];
    const int*   erows  = (const int*)  d_in[4];
    const int*   ecols  = (const int*)  d_in[5];
    const float* evals  = (const float*)d_in[6];
    const float* upref  = (const float*)d_in[7];
    const float* ipref  = (const float*)d_in[8];
    float* out = (float*)d_out;

    const size_t rowElems = (size_t)N_NODES * D;   // 9.6M

    char* base = (char*)d_ws;
    size_t off = 0;
    auto alloc = [&](size_t bytes) {
        char* p = base + off;
        off = (off + bytes + 255) & ~(size_t)255;
        return (void*)p;
    };
    ushort_t* p0     = (ushort_t*)alloc(rowElems * sizeof(ushort_t)); // 19.2 MB
    ushort_t* p1     = (ushort_t*)alloc(rowElems * sizeof(ushort_t)); // 19.2 MB
    ushort_t* p2     = (ushort_t*)alloc(rowElems * sizeof(ushort_t)); // 19.2 MB
    ushort_t* p3     = (ushort_t*)alloc(rowElems * sizeof(ushort_t)); // 19.2 MB
    unsigned* es     = (unsigned*)alloc((size_t)NNZ * sizeof(unsigned)); // 9.6 MB
    int*      hist   = (int*)     alloc((size_t)NH * sizeof(int));    // 0.6 MB
    int*      rowptr = (int*)     alloc((size_t)NH * sizeof(int));    // 0.6 MB
    int*      cursor = (int*)     alloc((size_t)NH * sizeof(int));    // 0.6 MB
    int*      bsums  = (int*)     alloc(1024 * sizeof(int));

    // ---- CSR build: counting sort with global atomics (low contention) ----
    hipMemsetAsync(hist, 0, (size_t)NH * sizeof(int), stream);
    row_hist   <<<2048, 256, 0, stream>>>(erows, hist);
    scan1_kernel<<<NBH, 256, 0, stream>>>(hist, rowptr, bsums, NH);
    scan3_kernel<<<NBH, 256, 0, stream>>>(rowptr, cursor, bsums, NH);
    csr_scatter<<<2048, 256, 0, stream>>>(erows, ecols, evals, cursor, es);

    // ---- GCN layers (no acc array; layers kept separately in bf16) ----
    init_kernel<<<(N_NODES + 3) / 4, 256, 0, stream>>>(upref, ipref, p0);
    gather_kernel<<<(N_NODES + 3) / 4, 256, 0, stream>>>(rowptr, es, p0, p1);
    gather_kernel<<<(N_NODES + 3) / 4, 256, 0, stream>>>(rowptr, es, p1, p2);
    gather_kernel<<<(N_NODES + 3) / 4, 256, 0, stream>>>(rowptr, es, p2, p3);

    score_kernel<<<(BATCH + 3) / 4, 256, 0, stream>>>(users, adj, weak, strong,
                                                      p0, p1, p2, p3, out);
}

// Round 3
// 382.867 us; speedup vs baseline: 1.4451x; 1.4451x over previous
//
#include <hip/hip_runtime.h>
#include <math.h>

#define D 64
#define NUM_USERS 100000
#define NUM_ITEMS 50000
#define N_NODES 150000   // NUM_USERS + NUM_ITEMS
#define NNZ 2400000
#define BATCH 8192
#define NEG_SLOPE 0.1f
#define EPS_NRM 1e-12f

// bucket geometry: bucket = row >> 8 (256 rows/bucket)
#define NBUCKET 586                 // ceil(150000/256)
#define NCHUNK  256
#define CH      9376                // chunk elems; 16B-aligned bases (9376*4 % 16 == 0)
#define NH      (NBUCKET * NCHUNK)  // 150016
#define NBH     (NH / 256)          // 586 scan blocks
#define CAP     6144                // LDS sorted-buffer capacity (mean 4096, ~32 sigma)
#define VSCALE  16383.f             // 14-bit val quantization

typedef unsigned short ushort_t;
typedef unsigned char  uchar_t;

__device__ __forceinline__ float wave_sum64(float v) {
    #pragma unroll
    for (int off = 32; off > 0; off >>= 1)
        v += __shfl_xor(v, off, 64);
    return v;
}

__device__ __forceinline__ int wave_sum64_i(int v) {
    #pragma unroll
    for (int off = 32; off > 0; off >>= 1)
        v += __shfl_xor(v, off, 64);
    return v;
}

__device__ __forceinline__ float bf2f(ushort_t u) {
    return __uint_as_float(((unsigned)u) << 16);
}
__device__ __forceinline__ ushort_t f2bf(float f) {
    unsigned x = __float_as_uint(f);
    unsigned r = (x + 0x7FFFu + ((x >> 16) & 1u)) >> 16;   // RNE
    return (ushort_t)r;
}

// ---------- CSR build: 2-level bucket sort, LDS int atomics only ----------

__global__ void bucket_hist(const int* __restrict__ rows, int* __restrict__ ht) {
    __shared__ int hist[NBUCKET];
    int c = blockIdx.x, tid = threadIdx.x;
    for (int b = tid; b < NBUCKET; b += 256) hist[b] = 0;
    __syncthreads();
    int base = c * CH;
    int n = NNZ - base; if (n > CH) n = CH;      // n always divisible by 4
    const int4* r4 = (const int4*)(rows + base);
    for (int i = tid; i < (n >> 2); i += 256) {
        int4 r = r4[i];
        atomicAdd(&hist[r.x >> 8], 1);
        atomicAdd(&hist[r.y >> 8], 1);
        atomicAdd(&hist[r.z >> 8], 1);
        atomicAdd(&hist[r.w >> 8], 1);
    }
    __syncthreads();
    for (int b = tid; b < NBUCKET; b += 256) ht[b * NCHUNK + c] = hist[b];
}

__global__ void scan1_kernel(const int* __restrict__ in, int* __restrict__ out,
                             int* __restrict__ bsums, int n) {
    int tid = threadIdx.x, gid = blockIdx.x * 256 + tid;
    int v = (gid < n) ? in[gid] : 0;
    int lane = tid & 63, w = tid >> 6;
    int s = v;
    #pragma unroll
    for (int off = 1; off < 64; off <<= 1) {
        int t = __shfl_up(s, off, 64);
        if (lane >= off) s += t;
    }
    __shared__ int wsum[4];
    if (lane == 63) wsum[w] = s;
    __syncthreads();
    if (tid == 0) {
        int a = 0;
        #pragma unroll
        for (int i = 0; i < 4; i++) { int t = wsum[i]; wsum[i] = a; a += t; }
    }
    __syncthreads();
    int incl = s + wsum[w];
    if (gid < n) out[gid] = incl - v;           // exclusive
    if (tid == 255) bsums[blockIdx.x] = incl;   // block total (unscanned)
}

// fused: each block reduces bsums[0..b) itself, then adds to its 256 elems
__global__ void scan3_kernel(int* __restrict__ out, const int* __restrict__ bsums, int n) {
    __shared__ int wtot[4];
    __shared__ int total;
    int b = blockIdx.x, tid = threadIdx.x;
    int lane = tid & 63, w = tid >> 6;
    int partial = 0;
    for (int i = tid; i < b; i += 256) partial += bsums[i];
    partial = wave_sum64_i(partial);
    if (lane == 0) wtot[w] = partial;
    __syncthreads();
    if (tid == 0) total = wtot[0] + wtot[1] + wtot[2] + wtot[3];
    __syncthreads();
    int gid = b * 256 + tid;
    if (gid < n) out[gid] += total;
}

// scatter into bucket-major intermediate: 4B final-format entry + 1B row-low key.
__global__ void __launch_bounds__(512) bucket_scatter(
        const int* __restrict__ rows, const int* __restrict__ cols,
        const float* __restrict__ vals, const int* __restrict__ hoff,
        unsigned* __restrict__ es4, uchar_t* __restrict__ rlow) {
    __shared__ int cur[NBUCKET];
    int c = blockIdx.x, tid = threadIdx.x;
    for (int b = tid; b < NBUCKET; b += 512) cur[b] = hoff[b * NCHUNK + c];
    __syncthreads();
    int base = c * CH;
    int n = NNZ - base; if (n > CH) n = CH;
    const int4*   r4 = (const int4*)(rows + base);
    const int4*   c4 = (const int4*)(cols + base);
    const float4* v4 = (const float4*)(vals + base);
    for (int i = tid; i < (n >> 2); i += 512) {
        int4 r = r4[i];
        int4 cc = c4[i];
        float4 v = v4[i];
        int p;
        p = atomicAdd(&cur[r.x >> 8], 1);
        es4[p] = (unsigned)cc.x | ((unsigned)(v.x * VSCALE + 0.5f) << 18);
        rlow[p] = (uchar_t)(r.x & 255);
        p = atomicAdd(&cur[r.y >> 8], 1);
        es4[p] = (unsigned)cc.y | ((unsigned)(v.y * VSCALE + 0.5f) << 18);
        rlow[p] = (uchar_t)(r.y & 255);
        p = atomicAdd(&cur[r.z >> 8], 1);
        es4[p] = (unsigned)cc.z | ((unsigned)(v.z * VSCALE + 0.5f) << 18);
        rlow[p] = (uchar_t)(r.z & 255);
        p = atomicAdd(&cur[r.w >> 8], 1);
        es4[p] = (unsigned)cc.w | ((unsigned)(v.w * VSCALE + 0.5f) << 18);
        rlow[p] = (uchar_t)(r.w & 255);
    }
}

// one block per bucket: hist on 1B keys, scan, permute 4B entries via LDS,
// coalesced dump. rowptr direct.
__global__ void __launch_bounds__(1024) bucket_sort(const unsigned* __restrict__ es4,
                                                    const uchar_t* __restrict__ rlow,
                                                    const int* __restrict__ hoff,
                                                    unsigned* __restrict__ es,
                                                    int* __restrict__ rowptr) {
    __shared__ int      hist[256];
    __shared__ int      wsum[4];
    __shared__ unsigned outbuf[CAP];    // 24 KB
    int b = blockIdx.x, tid = threadIdx.x;
    int beg = hoff[b * NCHUNK];
    int end = (b == NBUCKET - 1) ? NNZ : hoff[(b + 1) * NCHUNK];
    if (tid < 256) hist[tid] = 0;
    __syncthreads();
    for (int i = beg + tid; i < end; i += 1024)
        atomicAdd(&hist[rlow[i]], 1);
    __syncthreads();
    int excl = 0;
    if (tid < 256) {
        int v = hist[tid];
        int lane = tid & 63, w = tid >> 6;
        int s = v;
        #pragma unroll
        for (int off = 1; off < 64; off <<= 1) {
            int t = __shfl_up(s, off, 64);
            if (lane >= off) s += t;
        }
        if (lane == 63) wsum[w] = s;
        excl = s - v;
    }
    __syncthreads();
    if (tid == 0) {
        int a = 0;
        #pragma unroll
        for (int i = 0; i < 4; i++) { int t = wsum[i]; wsum[i] = a; a += t; }
    }
    __syncthreads();
    if (tid < 256) {
        excl += wsum[tid >> 6];
        int r = (b << 8) + tid;
        if (r <= N_NODES) rowptr[r] = beg + excl;
        hist[tid] = excl;           // reuse as cursor (bucket-relative)
    }
    __syncthreads();
    for (int i = beg + tid; i < end; i += 1024) {
        int d = atomicAdd(&hist[rlow[i]], 1);   // LDS int atomic
        outbuf[d] = es4[i];                     // L2-warm re-read, final format
    }
    __syncthreads();
    int n = end - beg;
    for (int i = tid; i < n; i += 1024)
        es[beg + i] = outbuf[i];                // coalesced dump
}

// ---------- GCN ----------
__global__ void init_kernel(const float* __restrict__ upref,
                            const float* __restrict__ ipref,
                            ushort_t* __restrict__ p0) {
    int row  = blockIdx.x * 4 + (threadIdx.x >> 6);
    int lane = threadIdx.x & 63;
    if (row >= N_NODES) return;
    float x = (row < NUM_USERS) ? upref[(size_t)row * D + lane]
                                : ipref[(size_t)(row - NUM_USERS) * D + lane];
    x = (x >= 0.f) ? x : NEG_SLOPE * x;
    float norm = sqrtf(wave_sum64(x * x));
    float y = x / fmaxf(norm, EPS_NRM);
    p0[(size_t)row * D + lane] = f2bf(y);
}

// one wave per row; 8 edge-slots (sub = lane>>3), 8 features/lane (fl = lane&7);
// 2x unrolled; es entries are 4B packed col(18)|valq(14).
// Epilogue: transpose-butterfly over sub bits so lane (sub,fl) ends holding the
// full sum for feature fl*8+sub -> one lrelu/f2bf/2B-store per lane, no divergence.
__global__ void gather_kernel(const int* __restrict__ rowptr,
                              const unsigned* __restrict__ es,
                              const ushort_t* __restrict__ p,
                              ushort_t* __restrict__ pn) {
    int row  = blockIdx.x * 4 + (threadIdx.x >> 6);
    int lane = threadIdx.x & 63;
    if (row >= N_NODES) return;
    int sub = lane >> 3;
    int fl  = lane & 7;
    int beg = rowptr[row], end = rowptr[row + 1];

    float a[8];
    #pragma unroll
    for (int k = 0; k < 8; k++) a[k] = 0.f;

    const float vs = 1.f / VSCALE;
    int e = beg + sub;
    while (e + 8 < end) {
        unsigned ev0 = es[e];
        unsigned ev1 = es[e + 8];
        const uint4 q0 = *(const uint4*)(p + (((ev0 & 0x3FFFFu) << 6) | (fl << 3)));
        const uint4 q1 = *(const uint4*)(p + (((ev1 & 0x3FFFFu) << 6) | (fl << 3)));
        float v0 = (float)(ev0 >> 18) * vs;
        float v1 = (float)(ev1 >> 18) * vs;
        a[0] = fmaf(v0, __uint_as_float(q0.x << 16),         a[0]);
        a[1] = fmaf(v0, __uint_as_float(q0.x & 0xFFFF0000u), a[1]);
        a[2] = fmaf(v0, __uint_as_float(q0.y << 16),         a[2]);
        a[3] = fmaf(v0, __uint_as_float(q0.y & 0xFFFF0000u), a[3]);
        a[4] = fmaf(v0, __uint_as_float(q0.z << 16),         a[4]);
        a[5] = fmaf(v0, __uint_as_float(q0.z & 0xFFFF0000u), a[5]);
        a[6] = fmaf(v0, __uint_as_float(q0.w << 16),         a[6]);
        a[7] = fmaf(v0, __uint_as_float(q0.w & 0xFFFF0000u), a[7]);
        a[0] = fmaf(v1, __uint_as_float(q1.x << 16),         a[0]);
        a[1] = fmaf(v1, __uint_as_float(q1.x & 0xFFFF0000u), a[1]);
        a[2] = fmaf(v1, __uint_as_float(q1.y << 16),         a[2]);
        a[3] = fmaf(v1, __uint_as_float(q1.y & 0xFFFF0000u), a[3]);
        a[4] = fmaf(v1, __uint_as_float(q1.z << 16),         a[4]);
        a[5] = fmaf(v1, __uint_as_float(q1.z & 0xFFFF0000u), a[5]);
        a[6] = fmaf(v1, __uint_as_float(q1.w << 16),         a[6]);
        a[7] = fmaf(v1, __uint_as_float(q1.w & 0xFFFF0000u), a[7]);
        e += 16;
    }
    if (e < end) {
        unsigned ev = es[e];
        const uint4 q = *(const uint4*)(p + (((ev & 0x3FFFFu) << 6) | (fl << 3)));
        float v = (float)(ev >> 18) * vs;
        a[0] = fmaf(v, __uint_as_float(q.x << 16),         a[0]);
        a[1] = fmaf(v, __uint_as_float(q.x & 0xFFFF0000u), a[1]);
        a[2] = fmaf(v, __uint_as_float(q.y << 16),         a[2]);
        a[3] = fmaf(v, __uint_as_float(q.y & 0xFFFF0000u), a[3]);
        a[4] = fmaf(v, __uint_as_float(q.z << 16),         a[4]);
        a[5] = fmaf(v, __uint_as_float(q.z & 0xFFFF0000u), a[5]);
        a[6] = fmaf(v, __uint_as_float(q.w << 16),         a[6]);
        a[7] = fmaf(v, __uint_as_float(q.w & 0xFFFF0000u), a[7]);
    }

    // --- transpose-butterfly reduce over the 8 sub-groups ---
    bool s0 = (sub & 1) != 0, s1 = (sub & 2) != 0, s2 = (sub & 4) != 0;
    float b[4];
    #pragma unroll
    for (int j = 0; j < 4; j++) {
        float send = s0 ? a[2 * j]     : a[2 * j + 1];
        float keep = s0 ? a[2 * j + 1] : a[2 * j];
        b[j] = keep + __shfl_xor(send, 8, 64);
    }
    float c[2];
    #pragma unroll
    for (int i = 0; i < 2; i++) {
        float send = s1 ? b[2 * i]     : b[2 * i + 1];
        float keep = s1 ? b[2 * i + 1] : b[2 * i];
        c[i] = keep + __shfl_xor(send, 16, 64);
    }
    float y;
    {
        float send = s2 ? c[0] : c[1];
        float keep = s2 ? c[1] : c[0];
        y = keep + __shfl_xor(send, 32, 64);
    }

    // lane now owns feature fl*8+sub of this row
    y = (y >= 0.f) ? y : NEG_SLOPE * y;
    float ss = wave_sum64(y * y);
    float inv = 1.f / fmaxf(sqrtf(ss), EPS_NRM);
    pn[(size_t)row * D + fl * 8 + sub] = f2bf(y * inv);
}

// one wave per batch element: sum 4 layer rows for the user once, then 3 item dots.
__global__ void score_kernel(const int* __restrict__ users,
                             const int* __restrict__ it0,
                             const int* __restrict__ it1,
                             const int* __restrict__ it2,
                             const ushort_t* __restrict__ p0,
                             const ushort_t* __restrict__ p1,
                             const ushort_t* __restrict__ p2,
                             const ushort_t* __restrict__ p3,
                             float* __restrict__ out) {
    int b    = blockIdx.x * 4 + (threadIdx.x >> 6);
    int lane = threadIdx.x & 63;
    if (b >= BATCH) return;
    int u = users[b];
    size_t uo = (size_t)u * D + lane;
    float uf = bf2f(p0[uo]) + bf2f(p1[uo]) + bf2f(p2[uo]) + bf2f(p3[uo]);

    int its[3];
    its[0] = it0[b]; its[1] = it1[b]; its[2] = it2[b];
    #pragma unroll
    for (int k = 0; k < 3; k++) {
        size_t io = (size_t)(NUM_USERS + its[k]) * D + lane;
        float itf = bf2f(p0[io]) + bf2f(p1[io]) + bf2f(p2[io]) + bf2f(p3[io]);
        float s = wave_sum64(uf * itf) * 0.0625f;
        if (lane == 0)
            out[k * BATCH + b] = 1.f / (1.f + expf(-s));
    }
}

extern "C" void kernel_launch(void* const* d_in, const int* in_sizes, int n_in,
                              void* d_out, int out_size, void* d_ws, size_t ws_size,
                              hipStream_t stream) {
    const int*   users  = (const int*)  d_in[0];
    const int*   adj    = (const int*)  d_in[1];
    const int*   weak   = (const int*)  d_in[2];
    const int*   strong = (const int*)  d_in[3];
    const int*   erows  = (const int*)  d_in[4];
    const int*   ecols  = (const int*)  d_in[5];
    const float* evals  = (const float*)d_in[6];
    const float* upref  = (const float*)d_in[7];
    const float* ipref  = (const float*)d_in[8];
    float* out = (float*)d_out;

    const size_t rowElems = (size_t)N_NODES * D;   // 9.6M

    char* base = (char*)d_ws;
    size_t off = 0;
    auto alloc = [&](size_t bytes) {
        char* p = base + off;
        off = (off + bytes + 255) & ~(size_t)255;
        return (void*)p;
    };
    ushort_t* p0     = (ushort_t*)alloc(rowElems * sizeof(ushort_t)); // 19.2 MB
    ushort_t* p1     = (ushort_t*)alloc(rowElems * sizeof(ushort_t)); // 19.2 MB
    ushort_t* p2     = (ushort_t*)alloc(rowElems * sizeof(ushort_t)); // 19.2 MB
    ushort_t* p3     = (ushort_t*)alloc(rowElems * sizeof(ushort_t)); // 19.2 MB
    unsigned* es     = (unsigned*)alloc((size_t)NNZ * sizeof(unsigned)); // 9.6 MB
    int*      ht     = (int*)     alloc((size_t)NH * sizeof(int));    // 0.6 MB
    int*      hoff   = (int*)     alloc((size_t)NH * sizeof(int));    // 0.6 MB
    int*      rowptr = (int*)     alloc((N_NODES + 1) * sizeof(int));
    int*      bsums  = (int*)     alloc(1024 * sizeof(int));
    // intermediate (12 MB) aliases p2 (19.2 MB): p2 is first written by the
    // layer-2 gather, stream-ordered long after bucket_sort consumed these.
    unsigned* es4t   = (unsigned*)p2;                       // 9.6 MB
    uchar_t*  rlowt  = (uchar_t*)((char*)p2 + (size_t)NNZ * 4); // 2.4 MB (256-aligned)

    // ---- CSR build: bucket sort, zero global atomics ----
    bucket_hist   <<<NCHUNK, 256, 0, stream>>>(erows, ht);
    scan1_kernel  <<<NBH, 256, 0, stream>>>(ht, hoff, bsums, NH);
    scan3_kernel  <<<NBH, 256, 0, stream>>>(hoff, bsums, NH);
    bucket_scatter<<<NCHUNK, 512, 0, stream>>>(erows, ecols, evals, hoff, es4t, rlowt);
    bucket_sort   <<<NBUCKET, 1024, 0, stream>>>(es4t, rlowt, hoff, es, rowptr);

    // ---- GCN layers (no acc array; layers kept separately in bf16) ----
    init_kernel<<<(N_NODES + 3) / 4, 256, 0, stream>>>(upref, ipref, p0);
    gather_kernel<<<(N_NODES + 3) / 4, 256, 0, stream>>>(rowptr, es, p0, p1);
    gather_kernel<<<(N_NODES + 3) / 4, 256, 0, stream>>>(rowptr, es, p1, p2);
    gather_kernel<<<(N_NODES + 3) / 4, 256, 0, stream>>>(rowptr, es, p2, p3);

    score_kernel<<<(BATCH + 3) / 4, 256, 0, stream>>>(users, adj, weak, strong,
                                                      p0, p1, p2, p3, out);
}

// Round 4
// 372.725 us; speedup vs baseline: 1.4845x; 1.0272x over previous
//
#include <hip/hip_runtime.h>
#include <hip/hip_fp16.h>
#include <math.h>

#define D 64
#define NUM_USERS 100000
#define NUM_ITEMS 50000
#define N_NODES 150000   // NUM_USERS + NUM_ITEMS
#define NNZ 2400000
#define BATCH 8192
#define NEG_SLOPE 0.1f
#define EPS_NRM 1e-12f

// bucket geometry: bucket = row >> 9 (512 rows/bucket)
#define NB2     293                 // ceil(150000/512)
#define RPB     512                 // rows per bucket
#define NCHUNK  256
#define CH      9376                // chunk elems; 16B-aligned bases
#define NHT     (NB2 * NCHUNK)      // 75008 transposed hist entries
#define NBH     (NHT / 256)         // 293 scan blocks
#define CAP     10240               // LDS sorted-buffer capacity (mean 8192, +22 sigma)
#define VSCALE  16383.f             // 14-bit val quantization

typedef unsigned short ushort_t;

__device__ __forceinline__ float wave_sum64(float v) {
    #pragma unroll
    for (int off = 32; off > 0; off >>= 1)
        v += __shfl_xor(v, off, 64);
    return v;
}

__device__ __forceinline__ int wave_sum64_i(int v) {
    #pragma unroll
    for (int off = 32; off > 0; off >>= 1)
        v += __shfl_xor(v, off, 64);
    return v;
}

// fp16 helpers: extraction folds into v_fma_mix_f32 (op_sel) when fused.
__device__ __forceinline__ float h2f_lo(unsigned u) {
    return __half2float(__ushort_as_half((unsigned short)(u & 0xFFFFu)));
}
__device__ __forceinline__ float h2f_hi(unsigned u) {
    return __half2float(__ushort_as_half((unsigned short)(u >> 16)));
}

// ---------- CSR build: 2-level bucket sort, LDS int atomics only ----------

__global__ void bucket_hist(const int* __restrict__ rows, int* __restrict__ ht) {
    __shared__ int hist[NB2];
    int c = blockIdx.x, tid = threadIdx.x;
    for (int b = tid; b < NB2; b += 256) hist[b] = 0;
    __syncthreads();
    int base = c * CH;
    int n = NNZ - base; if (n > CH) n = CH;      // always divisible by 4
    const int4* r4 = (const int4*)(rows + base);
    for (int i = tid; i < (n >> 2); i += 256) {
        int4 r = r4[i];
        atomicAdd(&hist[r.x >> 9], 1);
        atomicAdd(&hist[r.y >> 9], 1);
        atomicAdd(&hist[r.z >> 9], 1);
        atomicAdd(&hist[r.w >> 9], 1);
    }
    __syncthreads();
    for (int b = tid; b < NB2; b += 256) ht[b * NCHUNK + c] = hist[b];
}

__global__ void scan1_kernel(const int* __restrict__ in, int* __restrict__ out,
                             int* __restrict__ bsums, int n) {
    int tid = threadIdx.x, gid = blockIdx.x * 256 + tid;
    int v = (gid < n) ? in[gid] : 0;
    int lane = tid & 63, w = tid >> 6;
    int s = v;
    #pragma unroll
    for (int off = 1; off < 64; off <<= 1) {
        int t = __shfl_up(s, off, 64);
        if (lane >= off) s += t;
    }
    __shared__ int wsum[4];
    if (lane == 63) wsum[w] = s;
    __syncthreads();
    if (tid == 0) {
        int a = 0;
        #pragma unroll
        for (int i = 0; i < 4; i++) { int t = wsum[i]; wsum[i] = a; a += t; }
    }
    __syncthreads();
    int incl = s + wsum[w];
    if (gid < n) out[gid] = incl - v;           // exclusive
    if (tid == 255) bsums[blockIdx.x] = incl;   // block total (unscanned)
}

// fused: each block reduces bsums[0..b) itself, then adds to its 256 elems
__global__ void scan3_kernel(int* __restrict__ out, const int* __restrict__ bsums, int n) {
    __shared__ int wtot[4];
    __shared__ int total;
    int b = blockIdx.x, tid = threadIdx.x;
    int lane = tid & 63, w = tid >> 6;
    int partial = 0;
    for (int i = tid; i < b; i += 256) partial += bsums[i];
    partial = wave_sum64_i(partial);
    if (lane == 0) wtot[w] = partial;
    __syncthreads();
    if (tid == 0) total = wtot[0] + wtot[1] + wtot[2] + wtot[3];
    __syncthreads();
    int gid = b * 256 + tid;
    if (gid < n) out[gid] += total;
}

// scatter into bucket-major intermediate: 4B final-format entry + 2B row-low key.
// ~32-entry runs per (chunk,bucket) -> full-line write utilization.
__global__ void __launch_bounds__(512) bucket_scatter(
        const int* __restrict__ rows, const int* __restrict__ cols,
        const float* __restrict__ vals, const int* __restrict__ hoff,
        unsigned* __restrict__ es4, ushort_t* __restrict__ rlow) {
    __shared__ int cur[NB2];
    int c = blockIdx.x, tid = threadIdx.x;
    for (int b = tid; b < NB2; b += 512) cur[b] = hoff[b * NCHUNK + c];
    __syncthreads();
    int base = c * CH;
    int n = NNZ - base; if (n > CH) n = CH;
    const int4*   r4 = (const int4*)(rows + base);
    const int4*   c4 = (const int4*)(cols + base);
    const float4* v4 = (const float4*)(vals + base);
    for (int i = tid; i < (n >> 2); i += 512) {
        int4 r = r4[i];
        int4 cc = c4[i];
        float4 v = v4[i];
        int p;
        p = atomicAdd(&cur[r.x >> 9], 1);
        es4[p] = (unsigned)cc.x | ((unsigned)(v.x * VSCALE + 0.5f) << 18);
        rlow[p] = (ushort_t)(r.x & (RPB - 1));
        p = atomicAdd(&cur[r.y >> 9], 1);
        es4[p] = (unsigned)cc.y | ((unsigned)(v.y * VSCALE + 0.5f) << 18);
        rlow[p] = (ushort_t)(r.y & (RPB - 1));
        p = atomicAdd(&cur[r.z >> 9], 1);
        es4[p] = (unsigned)cc.z | ((unsigned)(v.z * VSCALE + 0.5f) << 18);
        rlow[p] = (ushort_t)(r.z & (RPB - 1));
        p = atomicAdd(&cur[r.w >> 9], 1);
        es4[p] = (unsigned)cc.w | ((unsigned)(v.w * VSCALE + 0.5f) << 18);
        rlow[p] = (ushort_t)(r.w & (RPB - 1));
    }
}

// one block per bucket (~8192 edges): hist on 2B keys, 512-wide scan, permute
// 4B entries into LDS outbuf, coalesced dump. rowptr direct.
__global__ void __launch_bounds__(1024) bucket_sort(const unsigned* __restrict__ es4,
                                                    const ushort_t* __restrict__ rlow,
                                                    const int* __restrict__ hoff,
                                                    unsigned* __restrict__ es,
                                                    int* __restrict__ rowptr) {
    __shared__ int      hist[RPB];
    __shared__ int      wsum[8];
    __shared__ unsigned outbuf[CAP];    // 40 KB
    int b = blockIdx.x, tid = threadIdx.x;
    int beg = hoff[b * NCHUNK];
    int end = (b == NB2 - 1) ? NNZ : hoff[(b + 1) * NCHUNK];
    if (tid < RPB) hist[tid] = 0;
    __syncthreads();
    for (int i = beg + tid; i < end; i += 1024)
        atomicAdd(&hist[rlow[i]], 1);
    __syncthreads();
    int excl = 0;
    if (tid < RPB) {
        int v = hist[tid];
        int lane = tid & 63, w = tid >> 6;
        int s = v;
        #pragma unroll
        for (int off = 1; off < 64; off <<= 1) {
            int t = __shfl_up(s, off, 64);
            if (lane >= off) s += t;
        }
        if (lane == 63) wsum[w] = s;
        excl = s - v;
    }
    __syncthreads();
    if (tid == 0) {
        int a = 0;
        #pragma unroll
        for (int i = 0; i < 8; i++) { int t = wsum[i]; wsum[i] = a; a += t; }
    }
    __syncthreads();
    if (tid < RPB) {
        excl += wsum[tid >> 6];
        int r = b * RPB + tid;
        if (r <= N_NODES) rowptr[r] = beg + excl;
        hist[tid] = excl;           // reuse as cursor (bucket-relative)
    }
    __syncthreads();
    for (int i = beg + tid; i < end; i += 1024) {
        int d = atomicAdd(&hist[rlow[i]], 1);   // LDS int atomic
        outbuf[d] = es4[i];                     // L2-warm re-read, final format
    }
    __syncthreads();
    int n = end - beg;
    for (int i = tid; i < n; i += 1024)
        es[beg + i] = outbuf[i];                // coalesced dump
}

// ---------- GCN ----------
__global__ void init_kernel(const float* __restrict__ upref,
                            const float* __restrict__ ipref,
                            __half* __restrict__ p0) {
    int row  = blockIdx.x * 4 + (threadIdx.x >> 6);
    int lane = threadIdx.x & 63;
    if (row >= N_NODES) return;
    float x = (row < NUM_USERS) ? upref[(size_t)row * D + lane]
                                : ipref[(size_t)(row - NUM_USERS) * D + lane];
    x = (x >= 0.f) ? x : NEG_SLOPE * x;
    float norm = sqrtf(wave_sum64(x * x));
    float y = x / fmaxf(norm, EPS_NRM);
    p0[(size_t)row * D + lane] = __float2half(y);
}

__device__ __forceinline__ void acc8(float a[8], float v, uint4 q) {
    a[0] = fmaf(v, h2f_lo(q.x), a[0]);
    a[1] = fmaf(v, h2f_hi(q.x), a[1]);
    a[2] = fmaf(v, h2f_lo(q.y), a[2]);
    a[3] = fmaf(v, h2f_hi(q.y), a[3]);
    a[4] = fmaf(v, h2f_lo(q.z), a[4]);
    a[5] = fmaf(v, h2f_hi(q.z), a[5]);
    a[6] = fmaf(v, h2f_lo(q.w), a[6]);
    a[7] = fmaf(v, h2f_hi(q.w), a[7]);
}

// one wave per row; 8 edge-slots (sub = lane>>3), 8 features/lane (fl = lane&7);
// 2x unrolled; es entries are 4B packed col(18)|valq(14); p is fp16 so the
// half->f32 extract folds into v_fma_mix_f32.
// Epilogue: transpose-butterfly over sub bits so lane (sub,fl) ends holding the
// full sum for feature fl*8+sub -> one lrelu/f2h/2B-store per lane, no divergence.
__global__ void gather_kernel(const int* __restrict__ rowptr,
                              const unsigned* __restrict__ es,
                              const __half* __restrict__ p,
                              __half* __restrict__ pn) {
    int row  = blockIdx.x * 4 + (threadIdx.x >> 6);
    int lane = threadIdx.x & 63;
    if (row >= N_NODES) return;
    int sub = lane >> 3;
    int fl  = lane & 7;
    int beg = rowptr[row], end = rowptr[row + 1];

    float a[8];
    #pragma unroll
    for (int k = 0; k < 8; k++) a[k] = 0.f;

    const float vs = 1.f / VSCALE;
    int e = beg + sub;
    while (e + 8 < end) {
        unsigned ev0 = es[e];
        unsigned ev1 = es[e + 8];
        const uint4 q0 = *(const uint4*)(p + (((ev0 & 0x3FFFFu) << 6) | (fl << 3)));
        const uint4 q1 = *(const uint4*)(p + (((ev1 & 0x3FFFFu) << 6) | (fl << 3)));
        float v0 = (float)(ev0 >> 18) * vs;
        float v1 = (float)(ev1 >> 18) * vs;
        acc8(a, v0, q0);
        acc8(a, v1, q1);
        e += 16;
    }
    if (e < end) {
        unsigned ev = es[e];
        const uint4 q = *(const uint4*)(p + (((ev & 0x3FFFFu) << 6) | (fl << 3)));
        float v = (float)(ev >> 18) * vs;
        acc8(a, v, q);
    }

    // --- transpose-butterfly reduce over the 8 sub-groups ---
    bool s0 = (sub & 1) != 0, s1 = (sub & 2) != 0, s2 = (sub & 4) != 0;
    float b[4];
    #pragma unroll
    for (int j = 0; j < 4; j++) {
        float send = s0 ? a[2 * j]     : a[2 * j + 1];
        float keep = s0 ? a[2 * j + 1] : a[2 * j];
        b[j] = keep + __shfl_xor(send, 8, 64);
    }
    float c[2];
    #pragma unroll
    for (int i = 0; i < 2; i++) {
        float send = s1 ? b[2 * i]     : b[2 * i + 1];
        float keep = s1 ? b[2 * i + 1] : b[2 * i];
        c[i] = keep + __shfl_xor(send, 16, 64);
    }
    float y;
    {
        float send = s2 ? c[0] : c[1];
        float keep = s2 ? c[1] : c[0];
        y = keep + __shfl_xor(send, 32, 64);
    }

    // lane now owns feature fl*8+sub of this row
    y = (y >= 0.f) ? y : NEG_SLOPE * y;
    float ss = wave_sum64(y * y);
    float inv = 1.f / fmaxf(sqrtf(ss), EPS_NRM);
    pn[(size_t)row * D + fl * 8 + sub] = __float2half(y * inv);
}

// one wave per batch element: sum 4 layer rows for the user once, then 3 item dots.
__global__ void score_kernel(const int* __restrict__ users,
                             const int* __restrict__ it0,
                             const int* __restrict__ it1,
                             const int* __restrict__ it2,
                             const __half* __restrict__ p0,
                             const __half* __restrict__ p1,
                             const __half* __restrict__ p2,
                             const __half* __restrict__ p3,
                             float* __restrict__ out) {
    int b    = blockIdx.x * 4 + (threadIdx.x >> 6);
    int lane = threadIdx.x & 63;
    if (b >= BATCH) return;
    int u = users[b];
    size_t uo = (size_t)u * D + lane;
    float uf = __half2float(p0[uo]) + __half2float(p1[uo])
             + __half2float(p2[uo]) + __half2float(p3[uo]);

    int its[3];
    its[0] = it0[b]; its[1] = it1[b]; its[2] = it2[b];
    #pragma unroll
    for (int k = 0; k < 3; k++) {
        size_t io = (size_t)(NUM_USERS + its[k]) * D + lane;
        float itf = __half2float(p0[io]) + __half2float(p1[io])
                  + __half2float(p2[io]) + __half2float(p3[io]);
        float s = wave_sum64(uf * itf) * 0.0625f;
        if (lane == 0)
            out[k * BATCH + b] = 1.f / (1.f + expf(-s));
    }
}

extern "C" void kernel_launch(void* const* d_in, const int* in_sizes, int n_in,
                              void* d_out, int out_size, void* d_ws, size_t ws_size,
                              hipStream_t stream) {
    const int*   users  = (const int*)  d_in[0];
    const int*   adj    = (const int*)  d_in[1];
    const int*   weak   = (const int*)  d_in[2];
    const int*   strong = (const int*)  d_in[3];
    const int*   erows  = (const int*)  d_in[4];
    const int*   ecols  = (const int*)  d_in[5];
    const float* evals  = (const float*)d_in[6];
    const float* upref  = (const float*)d_in[7];
    const float* ipref  = (const float*)d_in[8];
    float* out = (float*)d_out;

    const size_t rowElems = (size_t)N_NODES * D;   // 9.6M

    char* base = (char*)d_ws;
    size_t off = 0;
    auto alloc = [&](size_t bytes) {
        char* p = base + off;
        off = (off + bytes + 255) & ~(size_t)255;
        return (void*)p;
    };
    __half*   p0     = (__half*)  alloc(rowElems * sizeof(__half));   // 19.2 MB
    __half*   p1     = (__half*)  alloc(rowElems * sizeof(__half));   // 19.2 MB
    __half*   p2     = (__half*)  alloc(rowElems * sizeof(__half));   // 19.2 MB
    __half*   p3     = (__half*)  alloc(rowElems * sizeof(__half));   // 19.2 MB
    unsigned* es     = (unsigned*)alloc((size_t)NNZ * sizeof(unsigned)); // 9.6 MB
    int*      ht     = (int*)     alloc((size_t)NHT * sizeof(int));   // 0.3 MB
    int*      hoff   = (int*)     alloc((size_t)NHT * sizeof(int));   // 0.3 MB
    int*      rowptr = (int*)     alloc((N_NODES + 2) * sizeof(int));
    int*      bsums  = (int*)     alloc(1024 * sizeof(int));
    // intermediate (14.4 MB) aliases p2 (19.2 MB): p2 is first written by the
    // layer-2 gather, stream-ordered long after bucket_sort consumed these.
    unsigned* es4t   = (unsigned*)p2;                           // 9.6 MB
    ushort_t* rlowt  = (ushort_t*)((char*)p2 + (size_t)NNZ * 4); // 4.8 MB

    // ---- CSR build: bucket sort, zero global atomics ----
    bucket_hist   <<<NCHUNK, 256, 0, stream>>>(erows, ht);
    scan1_kernel  <<<NBH, 256, 0, stream>>>(ht, hoff, bsums, NHT);
    scan3_kernel  <<<NBH, 256, 0, stream>>>(hoff, bsums, NHT);
    bucket_scatter<<<NCHUNK, 512, 0, stream>>>(erows, ecols, evals, hoff, es4t, rlowt);
    bucket_sort   <<<NB2, 1024, 0, stream>>>(es4t, rlowt, hoff, es, rowptr);

    // ---- GCN layers (no acc array; layers kept separately in fp16) ----
    init_kernel<<<(N_NODES + 3) / 4, 256, 0, stream>>>(upref, ipref, p0);
    gather_kernel<<<(N_NODES + 3) / 4, 256, 0, stream>>>(rowptr, es, p0, p1);
    gather_kernel<<<(N_NODES + 3) / 4, 256, 0, stream>>>(rowptr, es, p1, p2);
    gather_kernel<<<(N_NODES + 3) / 4, 256, 0, stream>>>(rowptr, es, p2, p3);

    score_kernel<<<(BATCH + 3) / 4, 256, 0, stream>>>(users, adj, weak, strong,
                                                      p0, p1, p2, p3, out);
}

// Round 5
// 336.810 us; speedup vs baseline: 1.6428x; 1.1066x over previous
//
#include <hip/hip_runtime.h>
#include <hip/hip_fp16.h>
#include <math.h>

#define D 64
#define NUM_USERS 100000
#define NUM_ITEMS 50000
#define N_NODES 150000   // NUM_USERS + NUM_ITEMS
#define NNZ 2400000
#define BATCH 8192
#define NEG_SLOPE 0.1f
#define EPS_NRM 1e-12f

// bucket geometry: bucket = row >> 9 (512 rows/bucket)
#define NB2     293                 // ceil(150000/512)
#define RPB     512                 // rows per bucket
#define NCHUNK  256
#define CH      9376                // chunk elems; 16B-aligned bases
#define NHT     (NB2 * NCHUNK)      // 75008 transposed hist entries
#define NBH     (NHT / 256)         // 293 scan blocks
#define CAP     10240               // LDS sorted-buffer capacity (mean 8192, +22 sigma)
#define VSCALE  16383.f             // 14-bit val quantization

typedef unsigned short ushort_t;

__device__ __forceinline__ float wave_sum64(float v) {
    #pragma unroll
    for (int off = 32; off > 0; off >>= 1)
        v += __shfl_xor(v, off, 64);
    return v;
}

__device__ __forceinline__ int wave_sum64_i(int v) {
    #pragma unroll
    for (int off = 32; off > 0; off >>= 1)
        v += __shfl_xor(v, off, 64);
    return v;
}

// fp16 helpers: extraction folds into v_fma_mix_f32 (op_sel) when fused.
__device__ __forceinline__ float h2f_lo(unsigned u) {
    return __half2float(__ushort_as_half((unsigned short)(u & 0xFFFFu)));
}
__device__ __forceinline__ float h2f_hi(unsigned u) {
    return __half2float(__ushort_as_half((unsigned short)(u >> 16)));
}

// ---------- CSR build: 2-level bucket sort, LDS int atomics only ----------

__global__ void __launch_bounds__(512) bucket_hist(const int* __restrict__ rows,
                                                   int* __restrict__ ht) {
    __shared__ int hist[NB2];
    int c = blockIdx.x, tid = threadIdx.x;
    for (int b = tid; b < NB2; b += 512) hist[b] = 0;
    __syncthreads();
    int base = c * CH;
    int n = NNZ - base; if (n > CH) n = CH;      // always divisible by 4
    const int4* r4 = (const int4*)(rows + base);
    for (int i = tid; i < (n >> 2); i += 512) {
        int4 r = r4[i];
        atomicAdd(&hist[r.x >> 9], 1);
        atomicAdd(&hist[r.y >> 9], 1);
        atomicAdd(&hist[r.z >> 9], 1);
        atomicAdd(&hist[r.w >> 9], 1);
    }
    __syncthreads();
    for (int b = tid; b < NB2; b += 512) ht[b * NCHUNK + c] = hist[b];
}

__global__ void scan1_kernel(const int* __restrict__ in, int* __restrict__ out,
                             int* __restrict__ bsums, int n) {
    int tid = threadIdx.x, gid = blockIdx.x * 256 + tid;
    int v = (gid < n) ? in[gid] : 0;
    int lane = tid & 63, w = tid >> 6;
    int s = v;
    #pragma unroll
    for (int off = 1; off < 64; off <<= 1) {
        int t = __shfl_up(s, off, 64);
        if (lane >= off) s += t;
    }
    __shared__ int wsum[4];
    if (lane == 63) wsum[w] = s;
    __syncthreads();
    if (tid == 0) {
        int a = 0;
        #pragma unroll
        for (int i = 0; i < 4; i++) { int t = wsum[i]; wsum[i] = a; a += t; }
    }
    __syncthreads();
    int incl = s + wsum[w];
    if (gid < n) out[gid] = incl - v;           // exclusive
    if (tid == 255) bsums[blockIdx.x] = incl;   // block total (unscanned)
}

// fused: each block reduces bsums[0..b) itself, then adds to its 256 elems
__global__ void scan3_kernel(int* __restrict__ out, const int* __restrict__ bsums, int n) {
    __shared__ int wtot[4];
    __shared__ int total;
    int b = blockIdx.x, tid = threadIdx.x;
    int lane = tid & 63, w = tid >> 6;
    int partial = 0;
    for (int i = tid; i < b; i += 256) partial += bsums[i];
    partial = wave_sum64_i(partial);
    if (lane == 0) wtot[w] = partial;
    __syncthreads();
    if (tid == 0) total = wtot[0] + wtot[1] + wtot[2] + wtot[3];
    __syncthreads();
    int gid = b * 256 + tid;
    if (gid < n) out[gid] += total;
}

// scatter into bucket-major intermediate: 4B final-format entry + 2B row-low key.
// ~32-entry runs per (chunk,bucket) -> full-line write utilization.
// 1024 threads: scatter was grid-starved at 512 (occupancy 15%).
__global__ void __launch_bounds__(1024) bucket_scatter(
        const int* __restrict__ rows, const int* __restrict__ cols,
        const float* __restrict__ vals, const int* __restrict__ hoff,
        unsigned* __restrict__ es4, ushort_t* __restrict__ rlow) {
    __shared__ int cur[NB2];
    int c = blockIdx.x, tid = threadIdx.x;
    if (tid < NB2) cur[tid] = hoff[tid * NCHUNK + c];
    __syncthreads();
    int base = c * CH;
    int n = NNZ - base; if (n > CH) n = CH;
    const int4*   r4 = (const int4*)(rows + base);
    const int4*   c4 = (const int4*)(cols + base);
    const float4* v4 = (const float4*)(vals + base);
    for (int i = tid; i < (n >> 2); i += 1024) {
        int4 r = r4[i];
        int4 cc = c4[i];
        float4 v = v4[i];
        int p;
        p = atomicAdd(&cur[r.x >> 9], 1);
        es4[p] = (unsigned)cc.x | ((unsigned)(v.x * VSCALE + 0.5f) << 18);
        rlow[p] = (ushort_t)(r.x & (RPB - 1));
        p = atomicAdd(&cur[r.y >> 9], 1);
        es4[p] = (unsigned)cc.y | ((unsigned)(v.y * VSCALE + 0.5f) << 18);
        rlow[p] = (ushort_t)(r.y & (RPB - 1));
        p = atomicAdd(&cur[r.z >> 9], 1);
        es4[p] = (unsigned)cc.z | ((unsigned)(v.z * VSCALE + 0.5f) << 18);
        rlow[p] = (ushort_t)(r.z & (RPB - 1));
        p = atomicAdd(&cur[r.w >> 9], 1);
        es4[p] = (unsigned)cc.w | ((unsigned)(v.w * VSCALE + 0.5f) << 18);
        rlow[p] = (ushort_t)(r.w & (RPB - 1));
    }
}

// one block per bucket (~8192 edges): hist on 2B keys, 512-wide scan, permute
// 4B entries into LDS outbuf, coalesced dump. rowptr direct.
__global__ void __launch_bounds__(1024) bucket_sort(const unsigned* __restrict__ es4,
                                                    const ushort_t* __restrict__ rlow,
                                                    const int* __restrict__ hoff,
                                                    unsigned* __restrict__ es,
                                                    int* __restrict__ rowptr) {
    __shared__ int      hist[RPB];
    __shared__ int      wsum[8];
    __shared__ unsigned outbuf[CAP];    // 40 KB
    int b = blockIdx.x, tid = threadIdx.x;
    int beg = hoff[b * NCHUNK];
    int end = (b == NB2 - 1) ? NNZ : hoff[(b + 1) * NCHUNK];
    if (tid < RPB) hist[tid] = 0;
    __syncthreads();
    for (int i = beg + tid; i < end; i += 1024)
        atomicAdd(&hist[rlow[i]], 1);
    __syncthreads();
    int excl = 0;
    if (tid < RPB) {
        int v = hist[tid];
        int lane = tid & 63, w = tid >> 6;
        int s = v;
        #pragma unroll
        for (int off = 1; off < 64; off <<= 1) {
            int t = __shfl_up(s, off, 64);
            if (lane >= off) s += t;
        }
        if (lane == 63) wsum[w] = s;
        excl = s - v;
    }
    __syncthreads();
    if (tid == 0) {
        int a = 0;
        #pragma unroll
        for (int i = 0; i < 8; i++) { int t = wsum[i]; wsum[i] = a; a += t; }
    }
    __syncthreads();
    if (tid < RPB) {
        excl += wsum[tid >> 6];
        int r = b * RPB + tid;
        if (r <= N_NODES) rowptr[r] = beg + excl;
        hist[tid] = excl;           // reuse as cursor (bucket-relative)
    }
    __syncthreads();
    for (int i = beg + tid; i < end; i += 1024) {
        int d = atomicAdd(&hist[rlow[i]], 1);   // LDS int atomic
        outbuf[d] = es4[i];                     // L2-warm re-read, final format
    }
    __syncthreads();
    int n = end - beg;
    for (int i = tid; i < n; i += 1024)
        es[beg + i] = outbuf[i];                // coalesced dump
}

// ---------- GCN ----------
__global__ void init_kernel(const float* __restrict__ upref,
                            const float* __restrict__ ipref,
                            __half* __restrict__ p0) {
    int row  = blockIdx.x * 4 + (threadIdx.x >> 6);
    int lane = threadIdx.x & 63;
    if (row >= N_NODES) return;
    float x = (row < NUM_USERS) ? upref[(size_t)row * D + lane]
                                : ipref[(size_t)(row - NUM_USERS) * D + lane];
    x = (x >= 0.f) ? x : NEG_SLOPE * x;
    float norm = sqrtf(wave_sum64(x * x));
    float y = x / fmaxf(norm, EPS_NRM);
    p0[(size_t)row * D + lane] = __float2half(y);
}

__device__ __forceinline__ void acc8(float a[8], float v, uint4 q) {
    a[0] = fmaf(v, h2f_lo(q.x), a[0]);
    a[1] = fmaf(v, h2f_hi(q.x), a[1]);
    a[2] = fmaf(v, h2f_lo(q.y), a[2]);
    a[3] = fmaf(v, h2f_hi(q.y), a[3]);
    a[4] = fmaf(v, h2f_lo(q.z), a[4]);
    a[5] = fmaf(v, h2f_hi(q.z), a[5]);
    a[6] = fmaf(v, h2f_lo(q.w), a[6]);
    a[7] = fmaf(v, h2f_hi(q.w), a[7]);
}

// TWO rows per wave (32 lanes each): 4 edge-slots (sub = hl>>3), 8 features/lane
// (fl = hl&7); 2x unrolled; es entries are 4B packed col(18)|valq(14); p is fp16.
// Epilogue: 2-level transpose-butterfly over sub bits arranged so lane (sub,fl)
// ends holding ADJACENT features fl*8+2*sub, +1 -> one packed __half2 store.
// Amortizes the epilogue over 2 rows (was the dominant per-row cost).
__global__ void gather_kernel(const int* __restrict__ rowptr,
                              const unsigned* __restrict__ es,
                              const __half* __restrict__ p,
                              __half* __restrict__ pn) {
    int tid  = threadIdx.x;
    int row  = blockIdx.x * 8 + (tid >> 5);     // 8 rows per 256-thread block
    if (row >= N_NODES) return;
    int hl   = tid & 31;
    int sub  = hl >> 3;       // 0..3 edge slot
    int fl   = hl & 7;        // feature-octet index
    int beg = rowptr[row], end = rowptr[row + 1];

    float a[8];
    #pragma unroll
    for (int k = 0; k < 8; k++) a[k] = 0.f;

    const float vs = 1.f / VSCALE;
    int e = beg + sub;
    while (e + 4 < end) {
        unsigned ev0 = es[e];
        unsigned ev1 = es[e + 4];
        const uint4 q0 = *(const uint4*)(p + (((ev0 & 0x3FFFFu) << 6) | (fl << 3)));
        const uint4 q1 = *(const uint4*)(p + (((ev1 & 0x3FFFFu) << 6) | (fl << 3)));
        float v0 = (float)(ev0 >> 18) * vs;
        float v1 = (float)(ev1 >> 18) * vs;
        acc8(a, v0, q0);
        acc8(a, v1, q1);
        e += 8;
    }
    if (e < end) {
        unsigned ev = es[e];
        const uint4 q = *(const uint4*)(p + (((ev & 0x3FFFFu) << 6) | (fl << 3)));
        float v = (float)(ev >> 18) * vs;
        acc8(a, v, q);
    }

    // --- 2-level transpose-butterfly over the 4 sub-groups (within 32-lane half) ---
    // level 1 (xor 8, sub bit0): keep a-indices with bit1 == s0.
    bool s0 = (sub & 1) != 0, s1 = (sub & 2) != 0;
    float b1[4];
    #pragma unroll
    for (int j = 0; j < 4; j++) {
        int c4 = (j >> 1) * 4, bb = j & 1;
        float keep = s0 ? a[c4 + 2 + bb] : a[c4 + bb];
        float send = s0 ? a[c4 + bb]     : a[c4 + 2 + bb];
        b1[j] = keep + __shfl_xor(send, 8, 64);
    }
    // level 2 (xor 16, sub bit1): keep b1-indices with bit2 == s1.
    float cf[2];
    #pragma unroll
    for (int bb = 0; bb < 2; bb++) {
        float keep = s1 ? b1[2 + bb] : b1[bb];
        float send = s1 ? b1[bb]     : b1[2 + bb];
        cf[bb] = keep + __shfl_xor(send, 16, 64);
    }
    // lane now owns features fl*8 + 2*sub and fl*8 + 2*sub + 1 of this row
    float y0 = (cf[0] >= 0.f) ? cf[0] : NEG_SLOPE * cf[0];
    float y1 = (cf[1] >= 0.f) ? cf[1] : NEG_SLOPE * cf[1];
    float ss = fmaf(y0, y0, y1 * y1);
    ss += __shfl_xor(ss, 16, 64);
    ss += __shfl_xor(ss, 8, 64);
    ss += __shfl_xor(ss, 4, 64);
    ss += __shfl_xor(ss, 2, 64);
    ss += __shfl_xor(ss, 1, 64);
    float inv = 1.f / fmaxf(sqrtf(ss), EPS_NRM);
    __half2 o = __floats2half2_rn(y0 * inv, y1 * inv);
    *(__half2*)(pn + (size_t)row * D + fl * 8 + 2 * sub) = o;
}

// one wave per batch element: sum 4 layer rows for the user once, then 3 item dots.
__global__ void score_kernel(const int* __restrict__ users,
                             const int* __restrict__ it0,
                             const int* __restrict__ it1,
                             const int* __restrict__ it2,
                             const __half* __restrict__ p0,
                             const __half* __restrict__ p1,
                             const __half* __restrict__ p2,
                             const __half* __restrict__ p3,
                             float* __restrict__ out) {
    int b    = blockIdx.x * 4 + (threadIdx.x >> 6);
    int lane = threadIdx.x & 63;
    if (b >= BATCH) return;
    int u = users[b];
    size_t uo = (size_t)u * D + lane;
    float uf = __half2float(p0[uo]) + __half2float(p1[uo])
             + __half2float(p2[uo]) + __half2float(p3[uo]);

    int its[3];
    its[0] = it0[b]; its[1] = it1[b]; its[2] = it2[b];
    #pragma unroll
    for (int k = 0; k < 3; k++) {
        size_t io = (size_t)(NUM_USERS + its[k]) * D + lane;
        float itf = __half2float(p0[io]) + __half2float(p1[io])
                  + __half2float(p2[io]) + __half2float(p3[io]);
        float s = wave_sum64(uf * itf) * 0.0625f;
        if (lane == 0)
            out[k * BATCH + b] = 1.f / (1.f + expf(-s));
    }
}

extern "C" void kernel_launch(void* const* d_in, const int* in_sizes, int n_in,
                              void* d_out, int out_size, void* d_ws, size_t ws_size,
                              hipStream_t stream) {
    const int*   users  = (const int*)  d_in[0];
    const int*   adj    = (const int*)  d_in[1];
    const int*   weak   = (const int*)  d_in[2];
    const int*   strong = (const int*)  d_in[3];
    const int*   erows  = (const int*)  d_in[4];
    const int*   ecols  = (const int*)  d_in[5];
    const float* evals  = (const float*)d_in[6];
    const float* upref  = (const float*)d_in[7];
    const float* ipref  = (const float*)d_in[8];
    float* out = (float*)d_out;

    const size_t rowElems = (size_t)N_NODES * D;   // 9.6M

    char* base = (char*)d_ws;
    size_t off = 0;
    auto alloc = [&](size_t bytes) {
        char* p = base + off;
        off = (off + bytes + 255) & ~(size_t)255;
        return (void*)p;
    };
    __half*   p0     = (__half*)  alloc(rowElems * sizeof(__half));   // 19.2 MB
    __half*   p1     = (__half*)  alloc(rowElems * sizeof(__half));   // 19.2 MB
    __half*   p2     = (__half*)  alloc(rowElems * sizeof(__half));   // 19.2 MB
    __half*   p3     = (__half*)  alloc(rowElems * sizeof(__half));   // 19.2 MB
    unsigned* es     = (unsigned*)alloc((size_t)NNZ * sizeof(unsigned)); // 9.6 MB
    int*      ht     = (int*)     alloc((size_t)NHT * sizeof(int));   // 0.3 MB
    int*      hoff   = (int*)     alloc((size_t)NHT * sizeof(int));   // 0.3 MB
    int*      rowptr = (int*)     alloc((N_NODES + 2) * sizeof(int));
    int*      bsums  = (int*)     alloc(1024 * sizeof(int));
    // intermediate (14.4 MB) aliases p2 (19.2 MB): p2 is first written by the
    // layer-2 gather, stream-ordered long after bucket_sort consumed these.
    unsigned* es4t   = (unsigned*)p2;                           // 9.6 MB
    ushort_t* rlowt  = (ushort_t*)((char*)p2 + (size_t)NNZ * 4); // 4.8 MB

    // ---- CSR build: bucket sort, zero global atomics ----
    bucket_hist   <<<NCHUNK, 512, 0, stream>>>(erows, ht);
    scan1_kernel  <<<NBH, 256, 0, stream>>>(ht, hoff, bsums, NHT);
    scan3_kernel  <<<NBH, 256, 0, stream>>>(hoff, bsums, NHT);
    bucket_scatter<<<NCHUNK, 1024, 0, stream>>>(erows, ecols, evals, hoff, es4t, rlowt);
    bucket_sort   <<<NB2, 1024, 0, stream>>>(es4t, rlowt, hoff, es, rowptr);

    // ---- GCN layers (no acc array; layers kept separately in fp16) ----
    init_kernel<<<(N_NODES + 3) / 4, 256, 0, stream>>>(upref, ipref, p0);
    gather_kernel<<<N_NODES / 8, 256, 0, stream>>>(rowptr, es, p0, p1);   // 150000 % 8 == 0
    gather_kernel<<<N_NODES / 8, 256, 0, stream>>>(rowptr, es, p1, p2);
    gather_kernel<<<N_NODES / 8, 256, 0, stream>>>(rowptr, es, p2, p3);

    score_kernel<<<(BATCH + 3) / 4, 256, 0, stream>>>(users, adj, weak, strong,
                                                      p0, p1, p2, p3, out);
}